// Round 10
// baseline (133.098 us; speedup 1.0000x reference)
//
#include <hip/hip_runtime.h>
#include <hip/hip_bf16.h>

#define LSEQ 2048
#define BB   2048
#define TT   7
#define REC2 20                // [0..6] vn, [7..13] rn, [14] sc, [15] mc, [16] Lr

// ---------------------------------------------------------------------------
// Rank-1 chunk decomposition (see R8/R9): after a CC-step chunk the composite
// operator P is rank-1 to ~0.1^CC (fp32-exact for CC>=8): P = u v^T.
//   forward role:  v <- (v.E) o ee   -> vn (+ gold score/mask count)
//   backward role: r <- E.(ee o r)   -> rn, Lr  (u = P.1)
// logZ telescopes into independent junction terms -> flat combine + reduce.
// This round: KCH=128 (16-step chunks) doubles grid occupancy to 8 waves/SIMD,
// and a depth-2 prefetch pipeline doubles per-thread memory-level parallelism
// (R9 was latency-bound: VALUBusy 24%, BW 23%, occupancy grid-capped at 38%).
// NOTE: no min-wave launch_bounds (R5/R7: forcing it spills to scratch).
// ---------------------------------------------------------------------------
template<int KCH>
__global__ __launch_bounds__(256)
void crf_chunk_kernel(const float* __restrict__ em,
                      const int*   __restrict__ tags,
                      const int*   __restrict__ qmask,
                      const int*   __restrict__ mask,
                      const float* __restrict__ self_t,
                      const float* __restrict__ other_t,
                      float* __restrict__ recs) {
  constexpr int CC = LSEQ / KCH;
  __shared__ float sE[2][49];    // exp(transitions): [0]=self, [1]=other
  __shared__ float sT[2][49];    // raw transitions (gold-path score)
  int tid = threadIdx.x;
  if (tid < 49) {
    float sv = self_t[tid];
    float ov = other_t[tid];
    sE[0][tid] = __expf(sv);
    sE[1][tid] = __expf(ov);
    sT[0][tid] = sv;
    sT[1][tid] = ov;
  }
  __syncthreads();

  int role = tid >> 7;            // wave-uniform: 0 = forward v, 1 = backward r
  int g = blockIdx.x * 128 + (tid & 127);
  int b = g & (BB - 1);
  int c = g >> 11;                // uniform per block
  float* rp = recs + (size_t)g * REC2;

  float Es[49];                   // SGPR-resident via readfirstlane when uniform
  int loadedCont = -1;

  if (role == 0) {
    // ---------------- forward: vn + gold-path score ----------------
    float v[7];
#pragma unroll
    for (int t = 0; t < 7; ++t) v[t] = 1.0f;
    float sc = 0.0f;
    int   mc = 0;
    int i0 = c * CC, i_end = i0 + CC;
    int tp, qp;
    if (c == 0) {
      mc = mask[b]; tp = tags[b]; qp = qmask[b];
      i0 = 1;                     // step 0 is the alpha-init (junction kernel)
    } else {
      tp = tags[(size_t)(i0 - 1) * BB + b];
      qp = qmask[(size_t)(i0 - 1) * BB + b];
    }

    auto LD = [&](int i, float* e, int& tg, int& qm, int& mi) {
      int ii = (i < LSEQ) ? i : (LSEQ - 1);      // clamp (tail prefetch)
      size_t base = (size_t)ii * BB + b;
      const float* p = em + base * TT;
#pragma unroll
      for (int t = 0; t < 7; ++t) e[t] = p[t];
      tg = tags[base]; qm = qmask[base]; mi = mask[base];
    };

    float e0[7], e1[7], e2[7];
    int tg0, qm0, mi0, tg1, qm1, mi1, tg2, qm2, mi2;
    LD(i0,     e0, tg0, qm0, mi0);
    LD(i0 + 1, e1, tg1, qm1, mi1);

    int stepcnt = 0;
    for (int i = i0; i < i_end; ++i) {
      LD(i + 2, e2, tg2, qm2, mi2);              // depth-2 prefetch

      int cont = (qm0 != qp) ? 1 : 0;
      int cf = __builtin_amdgcn_readfirstlane(cont);
      bool uni = __all(cont == cf);
      float ee[7];
#pragma unroll
      for (int t = 0; t < 7; ++t) ee[t] = __expf(e0[t]);

      float etag = e0[0];
#pragma unroll
      for (int t = 1; t < 7; ++t) etag = (tg0 == t) ? e0[t] : etag;
      float ttag = sT[cont][tp * 7 + tg0];
      if (mi0) { sc += ttag + etag; ++mc; }
      tp = tg0; qp = qm0;

      if (uni) {
        if (cf != loadedCont) {
#pragma unroll
          for (int k = 0; k < 49; ++k)
            Es[k] = __int_as_float(
                __builtin_amdgcn_readfirstlane(__float_as_int(sE[cf][k])));
          loadedCont = cf;
        }
        float a[7] = {0.f,0.f,0.f,0.f,0.f,0.f,0.f};
#pragma unroll
        for (int r = 0; r < 7; ++r) {
          float vr = v[r];
#pragma unroll
          for (int t = 0; t < 7; ++t) a[t] = fmaf(vr, Es[r*7+t], a[t]);
        }
        if (!__any(mi0 == 0)) {
#pragma unroll
          for (int t = 0; t < 7; ++t) v[t] = a[t] * ee[t];
        } else {
#pragma unroll
          for (int t = 0; t < 7; ++t) v[t] = mi0 ? a[t] * ee[t] : v[t];
        }
      } else {
        loadedCont = -1;
        float a[7] = {0.f,0.f,0.f,0.f,0.f,0.f,0.f};
#pragma unroll
        for (int r = 0; r < 7; ++r) {
          float vr = v[r];
#pragma unroll
          for (int t = 0; t < 7; ++t) a[t] = fmaf(vr, sE[cont][r*7+t], a[t]);
        }
#pragma unroll
        for (int t = 0; t < 7; ++t) v[t] = mi0 ? a[t] * ee[t] : v[t];
      }

      if ((stepcnt & 7) == 7) {                  // overflow-guard renorm
        float s = v[0]+v[1]+v[2]+v[3]+v[4]+v[5]+v[6];
        float inv = 1.0f / s;
#pragma unroll
        for (int t = 0; t < 7; ++t) v[t] *= inv;
      }
      ++stepcnt;

#pragma unroll
      for (int t = 0; t < 7; ++t) { e0[t] = e1[t]; e1[t] = e2[t]; }
      tg0 = tg1; qm0 = qm1; mi0 = mi1;
      tg1 = tg2; qm1 = qm2; mi1 = mi2;
    }
    float s = v[0]+v[1]+v[2]+v[3]+v[4]+v[5]+v[6];
    float inv = 1.0f / s;
#pragma unroll
    for (int t = 0; t < 7; ++t) rp[t] = v[t] * inv;
    rp[14] = sc;
    rp[15] = (float)mc;
  } else {
    // ---------------- backward: rn, Lr  (u = P.1) ----------------
    float r[7];
#pragma unroll
    for (int t = 0; t < 7; ++t) r[t] = 1.0f;
    float Lr = 0.0f;
    int i_hi = c * CC + CC - 1;
    int i_lo = (c == 0) ? 1 : c * CC;

    auto LDB = [&](int i, float* e, int& q, int& mi) {
      int ii = (i > 0) ? i : 0;                  // clamp (tail prefetch)
      size_t base = (size_t)ii * BB + b;
      const float* p = em + base * TT;
#pragma unroll
      for (int t = 0; t < 7; ++t) e[t] = p[t];
      q = qmask[base]; mi = mask[base];
    };

    float e0[7], e1[7], e2[7];
    int q0, m0, q1, m1, q2, m2;
    LDB(i_hi,     e0, q0, m0);
    LDB(i_hi - 1, e1, q1, m1);

    int stepcnt = 0;
    for (int i = i_hi; i >= i_lo; --i) {
      LDB(i - 2, e2, q2, m2);                    // depth-2 prefetch

      int cont = (q0 != q1) ? 1 : 0;             // q1 = qmask[i-1]
      int cf = __builtin_amdgcn_readfirstlane(cont);
      bool uni = __all(cont == cf);
      float ee[7];
#pragma unroll
      for (int t = 0; t < 7; ++t) ee[t] = __expf(e0[t]);
      float tmp[7];
#pragma unroll
      for (int t = 0; t < 7; ++t) tmp[t] = ee[t] * r[t];

      if (uni) {
        if (cf != loadedCont) {
#pragma unroll
          for (int k = 0; k < 49; ++k)
            Es[k] = __int_as_float(
                __builtin_amdgcn_readfirstlane(__float_as_int(sE[cf][k])));
          loadedCont = cf;
        }
        float a[7] = {0.f,0.f,0.f,0.f,0.f,0.f,0.f};
#pragma unroll
        for (int t = 0; t < 7; ++t) {
          float tt = tmp[t];
#pragma unroll
          for (int s2 = 0; s2 < 7; ++s2) a[s2] = fmaf(tt, Es[s2*7+t], a[s2]);
        }
        if (!__any(m0 == 0)) {
#pragma unroll
          for (int s2 = 0; s2 < 7; ++s2) r[s2] = a[s2];
        } else {
#pragma unroll
          for (int s2 = 0; s2 < 7; ++s2) r[s2] = m0 ? a[s2] : r[s2];
        }
      } else {
        loadedCont = -1;
        float a[7] = {0.f,0.f,0.f,0.f,0.f,0.f,0.f};
#pragma unroll
        for (int t = 0; t < 7; ++t) {
          float tt = tmp[t];
#pragma unroll
          for (int s2 = 0; s2 < 7; ++s2) a[s2] = fmaf(tt, sE[cont][s2*7+t], a[s2]);
        }
#pragma unroll
        for (int s2 = 0; s2 < 7; ++s2) r[s2] = m0 ? a[s2] : r[s2];
      }

      if ((stepcnt & 7) == 7) {                  // renorm with log tracking
        float s = r[0]+r[1]+r[2]+r[3]+r[4]+r[5]+r[6];
        Lr += logf(s);
        float inv = 1.0f / s;
#pragma unroll
        for (int t = 0; t < 7; ++t) r[t] *= inv;
      }
      ++stepcnt;

#pragma unroll
      for (int t = 0; t < 7; ++t) { e0[t] = e1[t]; e1[t] = e2[t]; }
      q0 = q1; m0 = m1;
      q1 = q2; m1 = m2;
    }
    float s = r[0]+r[1]+r[2]+r[3]+r[4]+r[5]+r[6];
    Lr += logf(s);
    float inv = 1.0f / s;
#pragma unroll
    for (int t = 0; t < 7; ++t) rp[7 + t] = r[t] * inv;
    rp[16] = Lr;
  }
}

// ---------------------------------------------------------------------------
// Kernel 2: flat-parallel junction terms. term(b,c) = sc - Lr - log(dot),
// dot_0 = alpha0.rn_0 (+start/em0 gold terms), dot_c = vn_{c-1}.rn_c;
// c==K-1 additionally folds the final logZ term and end-transition score.
// ---------------------------------------------------------------------------
template<int KCH>
__global__ __launch_bounds__(256)
void crf_junction_kernel(const float* __restrict__ recs,
                         const float* __restrict__ em,
                         const int*   __restrict__ tags,
                         const float* __restrict__ start_t,
                         const float* __restrict__ end_t,
                         float* __restrict__ terms) {
  int g = blockIdx.x * 256 + threadIdx.x;
  int b = g & (BB - 1);
  int c = g >> 11;
  const float* rc = recs + (size_t)g * REC2;
  float rn[7];
#pragma unroll
  for (int t = 0; t < 7; ++t) rn[t] = rc[7 + t];
  float term = rc[14] - rc[16];          // sc - Lr
  float dot = 0.f;
  if (c == 0) {
    float e0[7], st[7];
#pragma unroll
    for (int t = 0; t < 7; ++t) { e0[t] = em[(size_t)b * TT + t]; st[t] = start_t[t]; }
#pragma unroll
    for (int t = 0; t < 7; ++t) dot = fmaf(__expf(st[t] + e0[t]), rn[t], dot);
    int tg0 = tags[b];
    float em0t = e0[0], stt = st[0];
#pragma unroll
    for (int t = 1; t < 7; ++t) {
      em0t = (tg0 == t) ? e0[t] : em0t;
      stt  = (tg0 == t) ? st[t] : stt;
    }
    term += stt + em0t;                  // gold start + em[0][tag0]
  } else {
    const float* rq = recs + (size_t)(g - BB) * REC2;
#pragma unroll
    for (int t = 0; t < 7; ++t) dot = fmaf(rq[t], rn[t], dot);
  }
  term -= logf(dot);
  if (c == KCH - 1) {
    float fz = 0.f;
#pragma unroll
    for (int t = 0; t < 7; ++t) fz = fmaf(rc[t], __expf(end_t[t]), fz);
    term -= logf(fz);                    // final logZ term (uses own vn)
    float mcf = 0.f;
    for (int cc = 0; cc < KCH; ++cc)
      mcf += recs[((size_t)cc * BB + b) * REC2 + 15];
    int se = (int)mcf - 1;
    int te = tags[(size_t)se * BB + b];
    term += end_t[te];                   // gold end transition
  }
  terms[g] = term;
}

// ---------------------------------------------------------------------------
// Kernel 3: deterministic tree-reduce of the junction terms.
// ---------------------------------------------------------------------------
__global__ __launch_bounds__(1024)
void crf_reduce_kernel(const float* __restrict__ terms, int n,
                       float* __restrict__ out) {
  __shared__ float s[1024];
  int t = threadIdx.x;
  float v = 0.f;
  for (int i = t; i < n; i += 1024) v += terms[i];
  s[t] = v;
  __syncthreads();
  for (int off = 512; off > 0; off >>= 1) {
    if (t < off) s[t] += s[t + off];
    __syncthreads();
  }
  if (t == 0) out[0] = s[0];
}

extern "C" void kernel_launch(void* const* d_in, const int* in_sizes, int n_in,
                              void* d_out, int out_size, void* d_ws, size_t ws_size,
                              hipStream_t stream) {
  const float* em      = (const float*)d_in[0];
  const int*   tags    = (const int*)d_in[1];
  const int*   qmask   = (const int*)d_in[2];
  const int*   mask    = (const int*)d_in[3];
  const float* start_t = (const float*)d_in[4];
  const float* end_t   = (const float*)d_in[5];
  const float* self_t  = (const float*)d_in[6];
  const float* other_t = (const float*)d_in[7];

  float* recs = (float*)d_ws;

  auto need = [](int kch) {
    return (size_t)kch * BB * (REC2 + 1) * sizeof(float);
  };

  if (ws_size >= need(128)) {
    constexpr int KCH = 128;
    int nchk = KCH * BB;
    float* terms = recs + (size_t)nchk * REC2;
    crf_chunk_kernel<KCH><<<(2 * nchk) / 256, 256, 0, stream>>>(
        em, tags, qmask, mask, self_t, other_t, recs);
    crf_junction_kernel<KCH><<<nchk / 256, 256, 0, stream>>>(
        recs, em, tags, start_t, end_t, terms);
    crf_reduce_kernel<<<1, 1024, 0, stream>>>(terms, nchk, (float*)d_out);
  } else {
    constexpr int KCH = 64;
    int nchk = KCH * BB;
    float* terms = recs + (size_t)nchk * REC2;
    crf_chunk_kernel<KCH><<<(2 * nchk) / 256, 256, 0, stream>>>(
        em, tags, qmask, mask, self_t, other_t, recs);
    crf_junction_kernel<KCH><<<nchk / 256, 256, 0, stream>>>(
        recs, em, tags, start_t, end_t, terms);
    crf_reduce_kernel<<<1, 1024, 0, stream>>>(terms, nchk, (float*)d_out);
  }
}

// Round 11
// 79.573 us; speedup vs baseline: 1.6727x; 1.6727x over previous
//
#include <hip/hip_runtime.h>
#include <hip/hip_bf16.h>

#define LSEQ 2048
#define BB   2048
#define TT   7
#define NFLD 17   // SoA fields: [0..6] vn, [7..13] rn, [14] sc, [15] mc, [16] Lr

// ---------------------------------------------------------------------------
// Rank-1 chunk decomposition (R8-R10): after a CC-step chunk the composite
// operator P is rank-1 to ~0.1^CC: P = u v^T.
//   forward role:  v <- (v.E) o ee   -> vn (+ gold score / mask count)
//   backward role: r <- E.(ee o r)   -> rn, Lr  (u = P.1)
// logZ telescopes into independent junction terms.
// This round: em rows are staged through LDS with coalesced float4 loads
// (R10 was L1-transaction-bound: 7 stride-28B scalar loads/step = ~196
// line-transactions per wave-step), records are SoA, reduce is hierarchical.
// NOTE: no min-wave launch_bounds (R5/R7: forcing it spills to scratch).
// ---------------------------------------------------------------------------
template<int KCH>
__global__ __launch_bounds__(256)
void crf_chunk_kernel(const float* __restrict__ em,
                      const int*   __restrict__ tags,
                      const int*   __restrict__ qmask,
                      const int*   __restrict__ mask,
                      const float* __restrict__ self_t,
                      const float* __restrict__ other_t,
                      float* __restrict__ recs) {
  constexpr int CC = LSEQ / KCH;
  constexpr int NG = KCH * BB;
  constexpr size_t ROWF = (size_t)BB * TT;     // floats per em step-row
  __shared__ float sE[2][49];
  __shared__ float sT[2][49];
  __shared__ float sF[2][896];   // fwd em rows: 128 b x 7 floats, double-buffered
  __shared__ float sB[2][896];   // bwd em rows

  int tid = threadIdx.x;
  if (tid < 49) {
    float sv = self_t[tid], ov = other_t[tid];
    sE[0][tid] = __expf(sv); sE[1][tid] = __expf(ov);
    sT[0][tid] = sv;         sT[1][tid] = ov;
  }

  int role = tid >> 7;           // 0 = forward, 1 = backward (wave-uniform)
  int k    = tid & 127;
  int g = blockIdx.x * 128 + k;
  int b = g & (BB - 1);
  int c = g >> 11;               // block-uniform (128 | 2048)
  int i_base = c * CC;
  int b0 = (blockIdx.x * 128) & (BB - 1);

  const float* fwd_base = em + ((size_t)i_base * BB + b0) * TT;
  const float* bwd_base = em + ((size_t)(i_base + CC - 1) * BB + b0) * TT;

  bool stager = (tid < 224);     // 224 x 16B = 3584 B = one row-block
  float4 fR, bR;
  if (stager) {
    fR = *reinterpret_cast<const float4*>(fwd_base + (size_t)tid * 4);
    bR = *reinterpret_cast<const float4*>(bwd_base + (size_t)tid * 4);
    *reinterpret_cast<float4*>(&sF[0][tid * 4]) = fR;
    *reinterpret_cast<float4*>(&sB[0][tid * 4]) = bR;
  }
  __syncthreads();

  float Es[49];                  // SGPR-resident via readfirstlane when uniform
  int loadedCont = -1;

  float v[7];
#pragma unroll
  for (int t = 0; t < 7; ++t) v[t] = 1.0f;
  float sc = 0.f, Lr = 0.f;
  int   mc = 0;
  int   tp = 0, qp = 0, q_i = 0;
  if (role == 0) {
    if (c == 0) { mc = mask[b]; tp = tags[b]; qp = qmask[b]; }
    else {
      tp = tags[(size_t)(i_base - 1) * BB + b];
      qp = qmask[(size_t)(i_base - 1) * BB + b];
    }
  } else {
    q_i = qmask[(size_t)(i_base + CC - 1) * BB + b];
  }

  int cur = 0;
  for (int j = 0; j < CC; ++j) {
    int jn = j + 1;
    if (stager && jn < CC) {     // issue next-step loads early (reg-buffered)
      fR = *reinterpret_cast<const float4*>(fwd_base + (size_t)jn * ROWF + (size_t)tid * 4);
      bR = *reinterpret_cast<const float4*>(bwd_base - (size_t)jn * ROWF + (size_t)tid * 4);
    }

    if (role == 0) {
      bool act = !(c == 0 && j == 0);          // block-uniform
      if (act) {
        int i = i_base + j;
        size_t base = (size_t)i * BB + b;
        int tg = tags[base];
        int qm = qmask[base];
        int mi = mask[base];
        float e[7];
#pragma unroll
        for (int t = 0; t < 7; ++t) e[t] = sF[cur][k * 7 + t];
        int cont = (qm != qp) ? 1 : 0;
        int cf = __builtin_amdgcn_readfirstlane(cont);
        bool uni = __all(cont == cf);
        float ee[7];
#pragma unroll
        for (int t = 0; t < 7; ++t) ee[t] = __expf(e[t]);
        float etag = sF[cur][k * 7 + tg];
        float ttag = sT[cont][tp * 7 + tg];
        if (mi) { sc += ttag + etag; ++mc; }
        tp = tg; qp = qm;

        if (uni) {
          if (cf != loadedCont) {
#pragma unroll
            for (int q = 0; q < 49; ++q)
              Es[q] = __int_as_float(
                  __builtin_amdgcn_readfirstlane(__float_as_int(sE[cf][q])));
            loadedCont = cf;
          }
          float a[7] = {0.f,0.f,0.f,0.f,0.f,0.f,0.f};
#pragma unroll
          for (int r = 0; r < 7; ++r) {
            float vr = v[r];
#pragma unroll
            for (int t = 0; t < 7; ++t) a[t] = fmaf(vr, Es[r*7+t], a[t]);
          }
          if (!__any(mi == 0)) {
#pragma unroll
            for (int t = 0; t < 7; ++t) v[t] = a[t] * ee[t];
          } else {
#pragma unroll
            for (int t = 0; t < 7; ++t) v[t] = mi ? a[t] * ee[t] : v[t];
          }
        } else {
          loadedCont = -1;
          float a[7] = {0.f,0.f,0.f,0.f,0.f,0.f,0.f};
#pragma unroll
          for (int r = 0; r < 7; ++r) {
            float vr = v[r];
#pragma unroll
            for (int t = 0; t < 7; ++t) a[t] = fmaf(vr, sE[cont][r*7+t], a[t]);
          }
#pragma unroll
          for (int t = 0; t < 7; ++t) v[t] = mi ? a[t] * ee[t] : v[t];
        }
        if ((j & 7) == 7) {                    // overflow-guard renorm
          float s = v[0]+v[1]+v[2]+v[3]+v[4]+v[5]+v[6];
          float inv = 1.0f / s;
#pragma unroll
          for (int t = 0; t < 7; ++t) v[t] *= inv;
        }
      }
    } else {
      int i = i_base + CC - 1 - j;
      bool act = !(c == 0 && j == CC - 1);     // block-uniform
      if (act) {
        size_t base = (size_t)i * BB + b;
        int q_im1 = qmask[base - BB];          // i >= 1 when act
        int mi = mask[base];
        float e[7];
#pragma unroll
        for (int t = 0; t < 7; ++t) e[t] = sB[cur][k * 7 + t];
        int cont = (q_i != q_im1) ? 1 : 0;
        int cf = __builtin_amdgcn_readfirstlane(cont);
        bool uni = __all(cont == cf);
        float ee[7];
#pragma unroll
        for (int t = 0; t < 7; ++t) ee[t] = __expf(e[t]);
        float tmp[7];
#pragma unroll
        for (int t = 0; t < 7; ++t) tmp[t] = ee[t] * v[t];

        if (uni) {
          if (cf != loadedCont) {
#pragma unroll
            for (int q = 0; q < 49; ++q)
              Es[q] = __int_as_float(
                  __builtin_amdgcn_readfirstlane(__float_as_int(sE[cf][q])));
            loadedCont = cf;
          }
          float a[7] = {0.f,0.f,0.f,0.f,0.f,0.f,0.f};
#pragma unroll
          for (int t = 0; t < 7; ++t) {
            float tt = tmp[t];
#pragma unroll
            for (int s2 = 0; s2 < 7; ++s2) a[s2] = fmaf(tt, Es[s2*7+t], a[s2]);
          }
          if (!__any(mi == 0)) {
#pragma unroll
            for (int s2 = 0; s2 < 7; ++s2) v[s2] = a[s2];
          } else {
#pragma unroll
            for (int s2 = 0; s2 < 7; ++s2) v[s2] = mi ? a[s2] : v[s2];
          }
        } else {
          loadedCont = -1;
          float a[7] = {0.f,0.f,0.f,0.f,0.f,0.f,0.f};
#pragma unroll
          for (int t = 0; t < 7; ++t) {
            float tt = tmp[t];
#pragma unroll
            for (int s2 = 0; s2 < 7; ++s2) a[s2] = fmaf(tt, sE[cont][s2*7+t], a[s2]);
          }
#pragma unroll
          for (int s2 = 0; s2 < 7; ++s2) v[s2] = mi ? a[s2] : v[s2];
        }
        q_i = q_im1;
        if ((j & 7) == 7) {                    // renorm with log tracking
          float s = v[0]+v[1]+v[2]+v[3]+v[4]+v[5]+v[6];
          Lr += logf(s);
          float inv = 1.0f / s;
#pragma unroll
          for (int t = 0; t < 7; ++t) v[t] *= inv;
        }
      }
    }

    if (stager && jn < CC) {     // write-late: regs -> next LDS buffer
      *reinterpret_cast<float4*>(&sF[cur ^ 1][tid * 4]) = fR;
      *reinterpret_cast<float4*>(&sB[cur ^ 1][tid * 4]) = bR;
    }
    __syncthreads();
    cur ^= 1;
  }

  // ---- epilogue: normalize and write SoA record (coalesced stores) ----
  float s = v[0]+v[1]+v[2]+v[3]+v[4]+v[5]+v[6];
  float inv = 1.0f / s;
  if (role == 0) {
#pragma unroll
    for (int t = 0; t < 7; ++t) recs[(size_t)t * NG + g] = v[t] * inv;
    recs[(size_t)14 * NG + g] = sc;
    recs[(size_t)15 * NG + g] = (float)mc;
  } else {
    Lr += logf(s);
#pragma unroll
    for (int t = 0; t < 7; ++t) recs[(size_t)(7 + t) * NG + g] = v[t] * inv;
    recs[(size_t)16 * NG + g] = Lr;
  }
}

// ---------------------------------------------------------------------------
// Kernel 2: flat-parallel junction terms + per-block tree reduction.
// term(b,c) = sc - Lr - log(dot); dot_0 = alpha0.rn_0 (+gold start terms),
// dot_c = vn_{c-1}.rn_c; c==KCH-1 folds the final logZ term and gold end.
// ---------------------------------------------------------------------------
template<int KCH>
__global__ __launch_bounds__(256)
void crf_junction_kernel(const float* __restrict__ recs,
                         const float* __restrict__ em,
                         const int*   __restrict__ tags,
                         const float* __restrict__ start_t,
                         const float* __restrict__ end_t,
                         float* __restrict__ partials) {
  constexpr int NG = KCH * BB;
  int tid = threadIdx.x;
  int g = blockIdx.x * 256 + tid;
  int b = g & (BB - 1);
  int c = g >> 11;                       // block-uniform (256 | 2048)
  float rn[7];
#pragma unroll
  for (int t = 0; t < 7; ++t) rn[t] = recs[(size_t)(7 + t) * NG + g];
  float term = recs[(size_t)14 * NG + g] - recs[(size_t)16 * NG + g];
  float dot = 0.f;
  if (c == 0) {
    float e0[7], st[7];
#pragma unroll
    for (int t = 0; t < 7; ++t) { e0[t] = em[(size_t)b * TT + t]; st[t] = start_t[t]; }
#pragma unroll
    for (int t = 0; t < 7; ++t) dot = fmaf(__expf(st[t] + e0[t]), rn[t], dot);
    int tg0 = tags[b];
    float em0t = e0[0], stt = st[0];
#pragma unroll
    for (int t = 1; t < 7; ++t) {
      em0t = (tg0 == t) ? e0[t] : em0t;
      stt  = (tg0 == t) ? st[t] : stt;
    }
    term += stt + em0t;                  // gold start + em[0][tag0]
  } else {
#pragma unroll
    for (int t = 0; t < 7; ++t)
      dot = fmaf(recs[(size_t)t * NG + (g - BB)], rn[t], dot);
  }
  term -= logf(dot);
  if (c == KCH - 1) {
    float fz = 0.f;
#pragma unroll
    for (int t = 0; t < 7; ++t)
      fz = fmaf(recs[(size_t)t * NG + g], __expf(end_t[t]), fz);
    term -= logf(fz);                    // final logZ term (own vn)
    float mcf = 0.f;
    for (int cc = 0; cc < KCH; ++cc)
      mcf += recs[(size_t)15 * NG + (size_t)cc * BB + b];
    int se = (int)mcf - 1;
    int te = tags[(size_t)se * BB + b];
    term += end_t[te];                   // gold end transition
  }
  __shared__ float red[256];
  red[tid] = term;
  __syncthreads();
  for (int off = 128; off > 0; off >>= 1) {
    if (tid < off) red[tid] += red[tid + off];
    __syncthreads();
  }
  if (tid == 0) partials[blockIdx.x] = red[0];
}

// ---------------------------------------------------------------------------
// Kernel 3: deterministic tree-reduce of the block partials.
// ---------------------------------------------------------------------------
__global__ __launch_bounds__(1024)
void crf_reduce_kernel(const float* __restrict__ partials, int n,
                       float* __restrict__ out) {
  __shared__ float s[1024];
  int t = threadIdx.x;
  float v = 0.f;
  for (int i = t; i < n; i += 1024) v += partials[i];
  s[t] = v;
  __syncthreads();
  for (int off = 512; off > 0; off >>= 1) {
    if (t < off) s[t] += s[t + off];
    __syncthreads();
  }
  if (t == 0) out[0] = s[0];
}

extern "C" void kernel_launch(void* const* d_in, const int* in_sizes, int n_in,
                              void* d_out, int out_size, void* d_ws, size_t ws_size,
                              hipStream_t stream) {
  const float* em      = (const float*)d_in[0];
  const int*   tags    = (const int*)d_in[1];
  const int*   qmask   = (const int*)d_in[2];
  const int*   mask    = (const int*)d_in[3];
  const float* start_t = (const float*)d_in[4];
  const float* end_t   = (const float*)d_in[5];
  const float* self_t  = (const float*)d_in[6];
  const float* other_t = (const float*)d_in[7];

  float* recs = (float*)d_ws;

  auto need = [](int kch) {
    size_t ng = (size_t)kch * BB;
    return (NFLD * ng + ng / 256) * sizeof(float);
  };

  if (ws_size >= need(128)) {
    constexpr int KCH = 128;
    constexpr int NG = KCH * BB;
    float* partials = recs + (size_t)NFLD * NG;
    crf_chunk_kernel<KCH><<<NG / 128, 256, 0, stream>>>(
        em, tags, qmask, mask, self_t, other_t, recs);
    crf_junction_kernel<KCH><<<NG / 256, 256, 0, stream>>>(
        recs, em, tags, start_t, end_t, partials);
    crf_reduce_kernel<<<1, 1024, 0, stream>>>(partials, NG / 256, (float*)d_out);
  } else {
    constexpr int KCH = 64;
    constexpr int NG = KCH * BB;
    float* partials = recs + (size_t)NFLD * NG;
    crf_chunk_kernel<KCH><<<NG / 128, 256, 0, stream>>>(
        em, tags, qmask, mask, self_t, other_t, recs);
    crf_junction_kernel<KCH><<<NG / 256, 256, 0, stream>>>(
        recs, em, tags, start_t, end_t, partials);
    crf_reduce_kernel<<<1, 1024, 0, stream>>>(partials, NG / 256, (float*)d_out);
  }
}

// Round 12
// 65.637 us; speedup vs baseline: 2.0278x; 1.2123x over previous
//
#include <hip/hip_runtime.h>
#include <hip/hip_bf16.h>

#define LSEQ 2048
#define BB   2048
#define TT   7
#define NFLD 17   // SoA fields: [0..6] vn, [7..13] rn, [14] sc, [15] mc, [16] Lr

typedef float f4 __attribute__((ext_vector_type(4)));

// Load 7 floats from a 4B-aligned row as two overlapping dwordx4 loads
// (bytes 0..15 and 12..27). gfx9+ global vector loads only need 4B alignment;
// memcpy keeps it UB-free. Cuts L1 line-transactions ~3.5x vs 7 scalar loads
// (wave footprint is 28 lines; touches = 28 * #instructions).
__device__ __forceinline__ void ld7(const float* __restrict__ p, float* e) {
  f4 lo, hi;
  __builtin_memcpy(&lo, p, 16);
  __builtin_memcpy(&hi, p + 3, 16);
  e[0] = lo.x; e[1] = lo.y; e[2] = lo.z; e[3] = lo.w;
  e[4] = hi.y; e[5] = hi.z; e[6] = hi.w;
}

// ---------------------------------------------------------------------------
// Rank-1 chunk decomposition (R8-R11): after a CC-step chunk the composite
// operator P is rank-1 to ~0.1^CC (< fp32 eps for CC >= 8): P = u v^T.
//   forward role:  v <- (v.E) o ee   -> vn (+ gold score / mask count)
//   backward role: r <- E.(ee o r)   -> rn, Lr  (u = P.1)
// logZ telescopes into independent junction terms -> flat combine + reduce.
// R10 was L1-transaction-bound (scalar em loads); R11's LDS staging stalled
// on per-step barriers. This round: R10's barrier-free depth-2 pipeline with
// vectorized overlapping em loads, unconditional cndmask masking, SoA records.
// NOTE: no min-wave launch_bounds (R5/R7: forcing it spills to scratch).
// ---------------------------------------------------------------------------
template<int KCH>
__global__ __launch_bounds__(256)
void crf_chunk_kernel(const float* __restrict__ em,
                      const int*   __restrict__ tags,
                      const int*   __restrict__ qmask,
                      const int*   __restrict__ mask,
                      const float* __restrict__ self_t,
                      const float* __restrict__ other_t,
                      float* __restrict__ recs) {
  constexpr int CC = LSEQ / KCH;
  constexpr int NG = KCH * BB;
  __shared__ float sE[2][49];    // exp(transitions): [0]=self, [1]=other
  __shared__ float sT[2][49];    // raw transitions (gold-path score)
  int tid = threadIdx.x;
  if (tid < 49) {
    float sv = self_t[tid], ov = other_t[tid];
    sE[0][tid] = __expf(sv); sE[1][tid] = __expf(ov);
    sT[0][tid] = sv;         sT[1][tid] = ov;
  }
  __syncthreads();

  int role = tid >> 7;            // wave-uniform: 0 = forward v, 1 = backward r
  int g = blockIdx.x * 128 + (tid & 127);
  int b = g & (BB - 1);
  int c = g >> 11;                // uniform per block

  float Es[49];                   // SGPR-resident via readfirstlane when uniform
  int loadedCont = -1;

  if (role == 0) {
    // ---------------- forward: vn + gold-path score ----------------
    float v[7];
#pragma unroll
    for (int t = 0; t < 7; ++t) v[t] = 1.0f;
    float sc = 0.0f;
    int   mc = 0;
    int i0 = c * CC, i_end = i0 + CC;
    int tp, qp;
    if (c == 0) {
      mc = mask[b]; tp = tags[b]; qp = qmask[b];
      i0 = 1;                     // step 0 is the alpha-init (junction kernel)
    } else {
      tp = tags[(size_t)(i0 - 1) * BB + b];
      qp = qmask[(size_t)(i0 - 1) * BB + b];
    }

    auto LD = [&](int i, float* e, int& tg, int& qm, int& mi) {
      int ii = (i < LSEQ) ? i : (LSEQ - 1);      // clamp (tail prefetch)
      size_t base = (size_t)ii * BB + b;
      ld7(em + base * TT, e);
      tg = tags[base]; qm = qmask[base]; mi = mask[base];
    };

    float e0[7], e1[7], e2[7];
    int tg0, qm0, mi0, tg1, qm1, mi1, tg2, qm2, mi2;
    LD(i0,     e0, tg0, qm0, mi0);
    LD(i0 + 1, e1, tg1, qm1, mi1);

    int stepcnt = 0;
    for (int i = i0; i < i_end; ++i) {
      LD(i + 2, e2, tg2, qm2, mi2);              // depth-2 prefetch

      int cont = (qm0 != qp) ? 1 : 0;
      int cf = __builtin_amdgcn_readfirstlane(cont);
      bool uni = __all(cont == cf);
      float ee[7];
#pragma unroll
      for (int t = 0; t < 7; ++t) ee[t] = __expf(e0[t]);

      float etag = e0[0];
#pragma unroll
      for (int t = 1; t < 7; ++t) etag = (tg0 == t) ? e0[t] : etag;
      float ttag = sT[cont][tp * 7 + tg0];
      if (mi0) { sc += ttag + etag; ++mc; }
      tp = tg0; qp = qm0;

      if (uni) {
        if (cf != loadedCont) {
#pragma unroll
          for (int k = 0; k < 49; ++k)
            Es[k] = __int_as_float(
                __builtin_amdgcn_readfirstlane(__float_as_int(sE[cf][k])));
          loadedCont = cf;
        }
        float a[7] = {0.f,0.f,0.f,0.f,0.f,0.f,0.f};
#pragma unroll
        for (int r = 0; r < 7; ++r) {
          float vr = v[r];
#pragma unroll
          for (int t = 0; t < 7; ++t) a[t] = fmaf(vr, Es[r*7+t], a[t]);
        }
#pragma unroll
        for (int t = 0; t < 7; ++t) v[t] = mi0 ? a[t] * ee[t] : v[t];
      } else {
        loadedCont = -1;
        float a[7] = {0.f,0.f,0.f,0.f,0.f,0.f,0.f};
#pragma unroll
        for (int r = 0; r < 7; ++r) {
          float vr = v[r];
#pragma unroll
          for (int t = 0; t < 7; ++t) a[t] = fmaf(vr, sE[cont][r*7+t], a[t]);
        }
#pragma unroll
        for (int t = 0; t < 7; ++t) v[t] = mi0 ? a[t] * ee[t] : v[t];
      }

      if ((stepcnt & 7) == 7) {                  // overflow-guard renorm
        float s = v[0]+v[1]+v[2]+v[3]+v[4]+v[5]+v[6];
        float inv = 1.0f / s;
#pragma unroll
        for (int t = 0; t < 7; ++t) v[t] *= inv;
      }
      ++stepcnt;

#pragma unroll
      for (int t = 0; t < 7; ++t) { e0[t] = e1[t]; e1[t] = e2[t]; }
      tg0 = tg1; qm0 = qm1; mi0 = mi1;
      tg1 = tg2; qm1 = qm2; mi1 = mi2;
    }
    float s = v[0]+v[1]+v[2]+v[3]+v[4]+v[5]+v[6];
    float inv = 1.0f / s;
#pragma unroll
    for (int t = 0; t < 7; ++t) recs[(size_t)t * NG + g] = v[t] * inv;
    recs[(size_t)14 * NG + g] = sc;
    recs[(size_t)15 * NG + g] = (float)mc;
  } else {
    // ---------------- backward: rn, Lr  (u = P.1) ----------------
    float r[7];
#pragma unroll
    for (int t = 0; t < 7; ++t) r[t] = 1.0f;
    float Lr = 0.0f;
    int i_hi = c * CC + CC - 1;
    int i_lo = (c == 0) ? 1 : c * CC;

    auto LDB = [&](int i, float* e, int& q, int& mi) {
      int ii = (i > 0) ? i : 0;                  // clamp (tail prefetch)
      size_t base = (size_t)ii * BB + b;
      ld7(em + base * TT, e);
      q = qmask[base]; mi = mask[base];
    };

    float e0[7], e1[7], e2[7];
    int q0, m0, q1, m1, q2, m2;
    LDB(i_hi,     e0, q0, m0);
    LDB(i_hi - 1, e1, q1, m1);

    int stepcnt = 0;
    for (int i = i_hi; i >= i_lo; --i) {
      LDB(i - 2, e2, q2, m2);                    // depth-2 prefetch

      int cont = (q0 != q1) ? 1 : 0;             // q1 = qmask[i-1]
      int cf = __builtin_amdgcn_readfirstlane(cont);
      bool uni = __all(cont == cf);
      float ee[7];
#pragma unroll
      for (int t = 0; t < 7; ++t) ee[t] = __expf(e0[t]);
      float tmp[7];
#pragma unroll
      for (int t = 0; t < 7; ++t) tmp[t] = ee[t] * r[t];

      if (uni) {
        if (cf != loadedCont) {
#pragma unroll
          for (int k = 0; k < 49; ++k)
            Es[k] = __int_as_float(
                __builtin_amdgcn_readfirstlane(__float_as_int(sE[cf][k])));
          loadedCont = cf;
        }
        float a[7] = {0.f,0.f,0.f,0.f,0.f,0.f,0.f};
#pragma unroll
        for (int t = 0; t < 7; ++t) {
          float tt = tmp[t];
#pragma unroll
          for (int s2 = 0; s2 < 7; ++s2) a[s2] = fmaf(tt, Es[s2*7+t], a[s2]);
        }
#pragma unroll
        for (int s2 = 0; s2 < 7; ++s2) r[s2] = m0 ? a[s2] : r[s2];
      } else {
        loadedCont = -1;
        float a[7] = {0.f,0.f,0.f,0.f,0.f,0.f,0.f};
#pragma unroll
        for (int t = 0; t < 7; ++t) {
          float tt = tmp[t];
#pragma unroll
          for (int s2 = 0; s2 < 7; ++s2) a[s2] = fmaf(tt, sE[cont][s2*7+t], a[s2]);
        }
#pragma unroll
        for (int s2 = 0; s2 < 7; ++s2) r[s2] = m0 ? a[s2] : r[s2];
      }

      if ((stepcnt & 7) == 7) {                  // renorm with log tracking
        float s = r[0]+r[1]+r[2]+r[3]+r[4]+r[5]+r[6];
        Lr += logf(s);
        float inv = 1.0f / s;
#pragma unroll
        for (int t = 0; t < 7; ++t) r[t] *= inv;
      }
      ++stepcnt;

#pragma unroll
      for (int t = 0; t < 7; ++t) { e0[t] = e1[t]; e1[t] = e2[t]; }
      q0 = q1; m0 = m1;
      q1 = q2; m1 = m2;
    }
    float s = r[0]+r[1]+r[2]+r[3]+r[4]+r[5]+r[6];
    Lr += logf(s);
    float inv = 1.0f / s;
#pragma unroll
    for (int t = 0; t < 7; ++t) recs[(size_t)(7 + t) * NG + g] = r[t] * inv;
    recs[(size_t)16 * NG + g] = Lr;
  }
}

// ---------------------------------------------------------------------------
// Kernel 2: flat-parallel junction terms + per-block tree reduction.
// term(b,c) = sc - Lr - log(dot); dot_0 = alpha0.rn_0 (+gold start terms),
// dot_c = vn_{c-1}.rn_c; c==KCH-1 folds the final logZ term and gold end.
// ---------------------------------------------------------------------------
template<int KCH>
__global__ __launch_bounds__(256)
void crf_junction_kernel(const float* __restrict__ recs,
                         const float* __restrict__ em,
                         const int*   __restrict__ tags,
                         const float* __restrict__ start_t,
                         const float* __restrict__ end_t,
                         float* __restrict__ partials) {
  constexpr int NG = KCH * BB;
  int tid = threadIdx.x;
  int g = blockIdx.x * 256 + tid;
  int b = g & (BB - 1);
  int c = g >> 11;                       // block-uniform (256 | 2048)
  float rn[7];
#pragma unroll
  for (int t = 0; t < 7; ++t) rn[t] = recs[(size_t)(7 + t) * NG + g];
  float term = recs[(size_t)14 * NG + g] - recs[(size_t)16 * NG + g];
  float dot = 0.f;
  if (c == 0) {
    float e0[7], st[7];
#pragma unroll
    for (int t = 0; t < 7; ++t) { e0[t] = em[(size_t)b * TT + t]; st[t] = start_t[t]; }
#pragma unroll
    for (int t = 0; t < 7; ++t) dot = fmaf(__expf(st[t] + e0[t]), rn[t], dot);
    int tg0 = tags[b];
    float em0t = e0[0], stt = st[0];
#pragma unroll
    for (int t = 1; t < 7; ++t) {
      em0t = (tg0 == t) ? e0[t] : em0t;
      stt  = (tg0 == t) ? st[t] : stt;
    }
    term += stt + em0t;                  // gold start + em[0][tag0]
  } else {
#pragma unroll
    for (int t = 0; t < 7; ++t)
      dot = fmaf(recs[(size_t)t * NG + (g - BB)], rn[t], dot);
  }
  term -= logf(dot);
  if (c == KCH - 1) {
    float fz = 0.f;
#pragma unroll
    for (int t = 0; t < 7; ++t)
      fz = fmaf(recs[(size_t)t * NG + g], __expf(end_t[t]), fz);
    term -= logf(fz);                    // final logZ term (own vn)
    float mcf = 0.f;
    for (int cc = 0; cc < KCH; ++cc)
      mcf += recs[(size_t)15 * NG + (size_t)cc * BB + b];
    int se = (int)mcf - 1;
    int te = tags[(size_t)se * BB + b];
    term += end_t[te];                   // gold end transition
  }
  __shared__ float red[256];
  red[tid] = term;
  __syncthreads();
  for (int off = 128; off > 0; off >>= 1) {
    if (tid < off) red[tid] += red[tid + off];
    __syncthreads();
  }
  if (tid == 0) partials[blockIdx.x] = red[0];
}

// ---------------------------------------------------------------------------
// Kernel 3: deterministic tree-reduce of the block partials.
// ---------------------------------------------------------------------------
__global__ __launch_bounds__(1024)
void crf_reduce_kernel(const float* __restrict__ partials, int n,
                       float* __restrict__ out) {
  __shared__ float s[1024];
  int t = threadIdx.x;
  float v = 0.f;
  for (int i = t; i < n; i += 1024) v += partials[i];
  s[t] = v;
  __syncthreads();
  for (int off = 512; off > 0; off >>= 1) {
    if (t < off) s[t] += s[t + off];
    __syncthreads();
  }
  if (t == 0) out[0] = s[0];
}

extern "C" void kernel_launch(void* const* d_in, const int* in_sizes, int n_in,
                              void* d_out, int out_size, void* d_ws, size_t ws_size,
                              hipStream_t stream) {
  const float* em      = (const float*)d_in[0];
  const int*   tags    = (const int*)d_in[1];
  const int*   qmask   = (const int*)d_in[2];
  const int*   mask    = (const int*)d_in[3];
  const float* start_t = (const float*)d_in[4];
  const float* end_t   = (const float*)d_in[5];
  const float* self_t  = (const float*)d_in[6];
  const float* other_t = (const float*)d_in[7];

  float* recs = (float*)d_ws;

  auto need = [](int kch) {
    size_t ng = (size_t)kch * BB;
    return (NFLD * ng + ng / 256) * sizeof(float);
  };

  if (ws_size >= need(128)) {
    constexpr int KCH = 128;
    constexpr int NG = KCH * BB;
    float* partials = recs + (size_t)NFLD * NG;
    crf_chunk_kernel<KCH><<<NG / 128, 256, 0, stream>>>(
        em, tags, qmask, mask, self_t, other_t, recs);
    crf_junction_kernel<KCH><<<NG / 256, 256, 0, stream>>>(
        recs, em, tags, start_t, end_t, partials);
    crf_reduce_kernel<<<1, 1024, 0, stream>>>(partials, NG / 256, (float*)d_out);
  } else {
    constexpr int KCH = 64;
    constexpr int NG = KCH * BB;
    float* partials = recs + (size_t)NFLD * NG;
    crf_chunk_kernel<KCH><<<NG / 128, 256, 0, stream>>>(
        em, tags, qmask, mask, self_t, other_t, recs);
    crf_junction_kernel<KCH><<<NG / 256, 256, 0, stream>>>(
        recs, em, tags, start_t, end_t, partials);
    crf_reduce_kernel<<<1, 1024, 0, stream>>>(partials, NG / 256, (float*)d_out);
  }
}